// Round 3
// baseline (143.576 us; speedup 1.0000x reference)
//
#include <hip/hip_runtime.h>
#include <hip/hip_bf16.h>

// INT4 group-quantized decode GEMM (M=64, K=8192, N=28672, GS=128).
// Round 3: A-fragments direct from L2 (g_wsa, no LDS); B-only LDS with
// 1x-amplification staging and one barrier per chunk (double-buffered);
// 256-thr blocks; verified 16x16x32 bf16 MFMA layouts.

typedef float  f32x4 __attribute__((ext_vector_type(4)));
typedef short  s16x8 __attribute__((ext_vector_type(8)));
typedef int    i32x4 __attribute__((ext_vector_type(4)));

#define K_DIM  8192
#define N_DIM  28672
#define BN     64
#define CK     128
#define NCHUNK (K_DIM / CK)   // 64

// A as bf16 cells: [c][k8][m], cell = 8 k-contiguous bf16 of row m.
__device__ s16x8 g_wsa[NCHUNK * 1024];

static __device__ __forceinline__ short f2bf(float f) {
    return (short)__builtin_bit_cast(unsigned short, __float2bfloat16(f));
}

__global__ __launch_bounds__(256)
void prep_a_kernel(const float* __restrict__ x) {
    const int tid = threadIdx.x;
    const int c   = blockIdx.x >> 2;        // 0..63
    const int mb  = blockIdx.x & 3;
    const int k8  = tid & 15;
    const int m   = mb * 16 + (tid >> 4);
    const float* src = x + (size_t)m * K_DIM + c * CK + k8 * 8;
    f32x4 a = *(const f32x4*)src;
    f32x4 b = *(const f32x4*)(src + 4);
    s16x8 o;
    o[0] = f2bf(a[0]); o[1] = f2bf(a[1]); o[2] = f2bf(a[2]); o[3] = f2bf(a[3]);
    o[4] = f2bf(b[0]); o[5] = f2bf(b[1]); o[6] = f2bf(b[2]); o[7] = f2bf(b[3]);
    g_wsa[(size_t)c * 1024 + k8 * 64 + m] = o;
}

__global__ __launch_bounds__(256, 3)
void int4gemm_kernel(const int*   __restrict__ qw,
                     const float* __restrict__ sc,
                     const int*   __restrict__ qz,
                     const float* __restrict__ bias,
                     float*       __restrict__ out)
{
    // B cells only, double-buffered: [buf][k8 0..15][col 0..63]
    __shared__ s16x8 lB[2][16 * 64];

    const int tid   = threadIdx.x;
    const int lane  = tid & 63;
    const int w     = tid >> 6;          // wave 0..3
    const int nbase = blockIdx.x * BN;

    // staging: thread owns ONE col, byte-rows 16w..16w+15 per chunk
    const int col = lane;

    // MFMA coords: wave(mh, nh) owns 2x2 grid of 16x16 tiles
    const int l15 = lane & 15;
    const int lk  = lane >> 4;           // 0..3
    const int mh  = w >> 1;              // 0..1
    const int nh  = w & 1;               // 0..1

    const int*   qcol = qw + nbase + col;
    const float* scol = sc + nbase + col;
    const int*   zcol = qz + nbase + col;

    f32x4 acc[2][2];
#pragma unroll
    for (int mi = 0; mi < 2; ++mi)
#pragma unroll
        for (int ni = 0; ni < 2; ++ni) acc[mi][ni] = (f32x4)0.0f;

    int   bvC[16], bvN[16];
    float sC, sN_;
    int   zC, zN_;

    // prologue: chunk 0 B bytes + scale/zero
#pragma unroll
    for (int u = 0; u < 16; ++u)
        bvC[u] = qcol[(size_t)(16 * w + u) * N_DIM];
    sC = scol[0];
    zC = zcol[0];

    const i32x4* wsa  = (const i32x4*)g_wsa;
    const int    aoff = lk * 64 + mh * 32 + l15;   // const part of A index

    for (int c = 0; c < NCHUNK; ++c) {
        const int cb = (c + 1) & (NCHUNK - 1);   // wraps at end; harmless reload

        // ---- issue next-chunk B + scale loads (land ~1 chunk-period later) ----
#pragma unroll
        for (int u = 0; u < 16; ++u)
            bvN[u] = qcol[(size_t)(cb * 64 + 16 * w + u) * N_DIM];
        sN_ = scol[(size_t)cb * N_DIM];
        zN_ = zcol[(size_t)cb * N_DIM];

        // ---- issue A-fragment loads for THIS chunk (L2-resident, ~200cy) ----
        i32x4 af[4][2];
#pragma unroll
        for (int ks = 0; ks < 4; ++ks)
#pragma unroll
            for (int mi = 0; mi < 2; ++mi)
                af[ks][mi] = wsa[(size_t)c * 1024 + ks * 256 + mi * 16 + aoff];

        // ---- dequant current chunk's 16 bytes -> 4 cells, write LDS ----
        const float s = sC;
        const float o = -(float)zC * s;
#pragma unroll
        for (int jp = 0; jp < 4; ++jp) {
            s16x8 cell;
#pragma unroll
            for (int uu = 0; uu < 4; ++uu) {
                const int v = bvC[4 * jp + uu];
                cell[2 * uu]     = f2bf(fmaf((float)(v & 15), s, o));
                cell[2 * uu + 1] = f2bf(fmaf((float)(v >> 4), s, o));
            }
            // lane-linear 16B writes: conflict-free
            lB[c & 1][(4 * w + jp) * 64 + col] = cell;
        }

        // single barrier per chunk: writes of buf[c&1] done; reads may begin.
        // (next chunk writes the OTHER buffer, so no second barrier needed)
        asm volatile("s_waitcnt lgkmcnt(0)" ::: "memory");
        asm volatile("s_barrier" ::: "memory");

        // ---- MFMA phase: 4 ksteps x 2x2 tiles ----
#pragma unroll
        for (int ks = 0; ks < 4; ++ks) {
            const int cidx = (ks * 4 + lk) * 64 + nh * 32 + l15;
            const s16x8 b0 = lB[c & 1][cidx];
            const s16x8 b1 = lB[c & 1][cidx + 16];
#pragma unroll
            for (int mi = 0; mi < 2; ++mi) {
                const s16x8 a = __builtin_bit_cast(s16x8, af[ks][mi]);
                acc[mi][0] = __builtin_amdgcn_mfma_f32_16x16x32_bf16(a, b0, acc[mi][0], 0, 0, 0);
                acc[mi][1] = __builtin_amdgcn_mfma_f32_16x16x32_bf16(a, b1, acc[mi][1], 0, 0, 0);
            }
        }

        // ---- rotate pipeline ----
#pragma unroll
        for (int u = 0; u < 16; ++u) bvC[u] = bvN[u];
        sC = sN_;
        zC = zN_;
    }

    // ---- epilogue: bias + store ----
#pragma unroll
    for (int ni = 0; ni < 2; ++ni) {
        const int   ncol = nbase + nh * 32 + ni * 16 + l15;
        const float bv   = bias[ncol];
#pragma unroll
        for (int mi = 0; mi < 2; ++mi) {
#pragma unroll
            for (int jj = 0; jj < 4; ++jj) {
                const int m = mh * 32 + mi * 16 + lk * 4 + jj;
                out[(size_t)m * N_DIM + ncol] = acc[mi][ni][jj] + bv;
            }
        }
    }
}

extern "C" void kernel_launch(void* const* d_in, const int* in_sizes, int n_in,
                              void* d_out, int out_size, void* d_ws, size_t ws_size,
                              hipStream_t stream) {
    const float* x    = (const float*)d_in[0];
    const int*   qw   = (const int*)d_in[1];
    const float* sc   = (const float*)d_in[2];
    const int*   qz   = (const int*)d_in[3];
    const float* bias = (const float*)d_in[4];
    float*       out  = (float*)d_out;

    prep_a_kernel<<<dim3(256), dim3(256), 0, stream>>>(x);
    int4gemm_kernel<<<dim3(N_DIM / BN), dim3(256), 0, stream>>>(qw, sc, qz, bias, out);
}